// Round 1
// baseline (516.250 us; speedup 1.0000x reference)
//
#include <hip/hip_runtime.h>
#include <hip/hip_bf16.h>

typedef float f32x4 __attribute__((ext_vector_type(4)));
typedef __bf16 bf16x8 __attribute__((ext_vector_type(8)));

#define NNODES 50000
#define NEDGES 800000
#define FIN 128
#define FHID 384
#define FOUT 256

__device__ __forceinline__ float bf_lo(unsigned u) { return __uint_as_float(u << 16); }
__device__ __forceinline__ float bf_hi(unsigned u) { return __uint_as_float(u & 0xffff0000u); }
__device__ __forceinline__ unsigned short f2bf(float f) {
  unsigned u = __float_as_uint(f);
  u += 0x7fffu + ((u >> 16) & 1u);
  return (unsigned short)(u >> 16);
}

// ---------- feature f32 -> bf16 (packed pairs in uint) ----------
__global__ void cvt_feat_kernel(const float* __restrict__ f, unsigned* __restrict__ o, int n4) {
  int i = blockIdx.x * blockDim.x + threadIdx.x;
  if (i >= n4) return;
  float4 v = *(const float4*)(f + (size_t)i * 4);
  unsigned lo = (unsigned)f2bf(v.x) | ((unsigned)f2bf(v.y) << 16);
  unsigned hi = (unsigned)f2bf(v.z) | ((unsigned)f2bf(v.w) << 16);
  *(uint2*)(o + (size_t)i * 2) = make_uint2(lo, hi);
}

// ---------- W [K][Nw] f32 -> Wt [Nw][K] bf16 ----------
__global__ void wt_kernel(const float* __restrict__ W, __bf16* __restrict__ Wt, int K, int Nw) {
  int i = blockIdx.x * blockDim.x + threadIdx.x;
  if (i >= K * Nw) return;
  int k = i / Nw, n = i % Nw;
  unsigned short b = f2bf(W[i]);
  Wt[(size_t)n * K + k] = *(__bf16*)&b;
}

// ---------- degrees ----------
__global__ void degree_kernel(const int* __restrict__ ei, int* __restrict__ dout, int* __restrict__ din) {
  int e = blockIdx.x * blockDim.x + threadIdx.x;
  if (e >= NEDGES) return;
  atomicAdd(&dout[ei[e]], 1);
  atomicAdd(&din[ei[NEDGES + e]], 1);
}

// ---------- norms = clip(deg,1)^-0.5 ----------
__global__ void norm_kernel(const int* __restrict__ dout, const int* __restrict__ din,
                            float* __restrict__ onorm, float* __restrict__ inorm) {
  int i = blockIdx.x * blockDim.x + threadIdx.x;
  if (i >= NNODES) return;
  int a = dout[i]; if (a < 1) a = 1;
  int b = din[i]; if (b < 1) b = 1;
  onorm[i] = rsqrtf((float)a);
  inorm[i] = rsqrtf((float)b);
}

// ---------- exclusive scan of din -> row_ptr[N+1], cursor[N] (single block) ----------
__global__ void scan_kernel(const int* __restrict__ deg, int* __restrict__ row_ptr,
                            int* __restrict__ cursor, int n) {
  __shared__ int sums[1024];
  int t = threadIdx.x;
  const int C = (n + 1023) / 1024;
  int beg = t * C, end = beg + C;
  if (end > n) end = n;
  int s = 0;
  for (int i = beg; i < end; ++i) s += deg[i];
  sums[t] = s;
  __syncthreads();
  for (int d = 1; d < 1024; d <<= 1) {
    int v = (t >= d) ? sums[t - d] : 0;
    __syncthreads();
    sums[t] += v;
    __syncthreads();
  }
  int run = sums[t] - s;  // exclusive offset
  for (int i = beg; i < end; ++i) {
    int v = deg[i];
    row_ptr[i] = run;
    cursor[i] = run;
    run += v;
  }
  if (t == 1023) row_ptr[n] = run;
}

// ---------- CSR fill (bucket by dst) ----------
__global__ void fill_kernel(const int* __restrict__ ei, int* __restrict__ cursor, int* __restrict__ csr) {
  int e = blockIdx.x * blockDim.x + threadIdx.x;
  if (e >= NEDGES) return;
  int d = ei[NEDGES + e];
  int pos = atomicAdd(&cursor[d], 1);
  csr[pos] = ei[e];
}

// ---------- aggregate 1: aggF[n] = in_norm[n] * sum_e out_norm[src]*feat[src], d=128, bf16 out ----------
__global__ __launch_bounds__(256) void agg1_kernel(
    const int* __restrict__ row_ptr, const int* __restrict__ csr_src,
    const float* __restrict__ onorm, const float* __restrict__ inorm,
    const unsigned* __restrict__ featb, unsigned* __restrict__ aggF) {
  int node = (blockIdx.x << 2) + (threadIdx.x >> 6);
  if (node >= NNODES) return;
  int lane = threadIdx.x & 63;
  int beg = row_ptr[node], end = row_ptr[node + 1];
  float a0 = 0.f, a1 = 0.f;
  int e = beg;
  for (; e + 2 <= end; e += 2) {
    int s0 = csr_src[e], s1 = csr_src[e + 1];
    float w0 = onorm[s0], w1 = onorm[s1];
    unsigned p0 = featb[(size_t)s0 * 64 + lane];
    unsigned p1 = featb[(size_t)s1 * 64 + lane];
    a0 = fmaf(w0, bf_lo(p0), a0); a1 = fmaf(w0, bf_hi(p0), a1);
    a0 = fmaf(w1, bf_lo(p1), a0); a1 = fmaf(w1, bf_hi(p1), a1);
  }
  if (e < end) {
    int s0 = csr_src[e];
    float w0 = onorm[s0];
    unsigned p0 = featb[(size_t)s0 * 64 + lane];
    a0 = fmaf(w0, bf_lo(p0), a0); a1 = fmaf(w0, bf_hi(p0), a1);
  }
  float inn = inorm[node];
  a0 *= inn; a1 *= inn;
  aggF[(size_t)node * 64 + lane] = (unsigned)f2bf(a0) | ((unsigned)f2bf(a1) << 16);
}

// ---------- aggregate 2: out[n] = in_norm[n]*sum_e out_norm[src]*h2[src] + b2, d=256, f32 out ----------
__global__ __launch_bounds__(256) void agg2_kernel(
    const int* __restrict__ row_ptr, const int* __restrict__ csr_src,
    const float* __restrict__ onorm, const float* __restrict__ inorm,
    const unsigned* __restrict__ h2u, const float* __restrict__ b2,
    float* __restrict__ out) {
  int node = (blockIdx.x << 2) + (threadIdx.x >> 6);
  if (node >= NNODES) return;
  int lane = threadIdx.x & 63;
  int beg = row_ptr[node], end = row_ptr[node + 1];
  float a0 = 0.f, a1 = 0.f, a2 = 0.f, a3 = 0.f;
  int e = beg;
  for (; e + 2 <= end; e += 2) {
    int s0 = csr_src[e], s1 = csr_src[e + 1];
    float w0 = onorm[s0], w1 = onorm[s1];
    uint2 q0 = *(const uint2*)(h2u + (size_t)s0 * 128 + (lane << 1));
    uint2 q1 = *(const uint2*)(h2u + (size_t)s1 * 128 + (lane << 1));
    a0 = fmaf(w0, bf_lo(q0.x), a0); a1 = fmaf(w0, bf_hi(q0.x), a1);
    a2 = fmaf(w0, bf_lo(q0.y), a2); a3 = fmaf(w0, bf_hi(q0.y), a3);
    a0 = fmaf(w1, bf_lo(q1.x), a0); a1 = fmaf(w1, bf_hi(q1.x), a1);
    a2 = fmaf(w1, bf_lo(q1.y), a2); a3 = fmaf(w1, bf_hi(q1.y), a3);
  }
  if (e < end) {
    int s0 = csr_src[e];
    float w0 = onorm[s0];
    uint2 q0 = *(const uint2*)(h2u + (size_t)s0 * 128 + (lane << 1));
    a0 = fmaf(w0, bf_lo(q0.x), a0); a1 = fmaf(w0, bf_hi(q0.x), a1);
    a2 = fmaf(w0, bf_lo(q0.y), a2); a3 = fmaf(w0, bf_hi(q0.y), a3);
  }
  float inn = inorm[node];
  float4 bv = *(const float4*)(b2 + (lane << 2));
  float4 r;
  r.x = fmaf(a0, inn, bv.x);
  r.y = fmaf(a1, inn, bv.y);
  r.z = fmaf(a2, inn, bv.z);
  r.w = fmaf(a3, inn, bv.w);
  *(float4*)(out + (size_t)node * FOUT + (lane << 2)) = r;
}

// ---------- GEMM: C[M][N](bf16) = A[M][K](bf16) @ Bt[N][K](bf16)^T, opt bias+relu ----------
__device__ __forceinline__ f32x4 mfma16(bf16x8 a, bf16x8 b, f32x4 c) {
  return __builtin_amdgcn_mfma_f32_16x16x32_bf16(a, b, c, 0, 0, 0);
}

__global__ __launch_bounds__(256) void gemm_bf16(
    const __bf16* __restrict__ A, const __bf16* __restrict__ Bt,
    const float* __restrict__ bias, __bf16* __restrict__ C,
    int M, int N, int K, int relu) {
  __shared__ __attribute__((aligned(16))) __bf16 As[128 * 64];
  __shared__ __attribute__((aligned(16))) __bf16 Bs[128 * 64];
  const int tid = threadIdx.x;
  const int lane = tid & 63;
  const int wave = tid >> 6;
  const int wm = (wave >> 1) << 6;
  const int wn = (wave & 1) << 6;
  const int r16 = lane & 15;
  const int kg = lane >> 4;
  const int m0 = blockIdx.x * 128;
  const int n0 = blockIdx.y * 128;
  f32x4 acc[4][4];
#pragma unroll
  for (int m = 0; m < 4; ++m)
#pragma unroll
    for (int n = 0; n < 4; ++n) acc[m][n] = f32x4{0.f, 0.f, 0.f, 0.f};

  for (int k0 = 0; k0 < K; k0 += 64) {
    __syncthreads();
#pragma unroll
    for (int i = 0; i < 4; ++i) {
      int c = tid + (i << 8);      // chunk 0..1023
      int row = c >> 3;            // 0..127
      int col = c & 7;             // 16B chunk in row
      int sw = ((col ^ (row & 7)) << 3);
      int ga = m0 + row;
      uint4 av = make_uint4(0u, 0u, 0u, 0u);
      if (ga < M) av = *(const uint4*)(A + (size_t)ga * K + k0 + (col << 3));
      *(uint4*)(As + row * 64 + sw) = av;
      uint4 bv = *(const uint4*)(Bt + (size_t)(n0 + row) * K + k0 + (col << 3));
      *(uint4*)(Bs + row * 64 + sw) = bv;
    }
    __syncthreads();
#pragma unroll
    for (int kk = 0; kk < 2; ++kk) {
      int kc = (kk << 2) + kg;   // logical 16B chunk 0..7
      bf16x8 a[4], b[4];
#pragma unroll
      for (int m = 0; m < 4; ++m) {
        int r = wm + (m << 4) + r16;
        a[m] = *(const bf16x8*)(As + r * 64 + ((kc ^ (r & 7)) << 3));
      }
#pragma unroll
      for (int n = 0; n < 4; ++n) {
        int r = wn + (n << 4) + r16;
        b[n] = *(const bf16x8*)(Bs + r * 64 + ((kc ^ (r & 7)) << 3));
      }
#pragma unroll
      for (int m = 0; m < 4; ++m)
#pragma unroll
        for (int n = 0; n < 4; ++n)
          acc[m][n] = mfma16(a[m], b[n], acc[m][n]);
    }
  }
  // epilogue: C row = m0+wm+m*16+kg*4+j, col = n0+wn+n*16+r16
#pragma unroll
  for (int n = 0; n < 4; ++n) {
    int col = n0 + wn + (n << 4) + r16;
    float bv = bias ? bias[col] : 0.f;
#pragma unroll
    for (int m = 0; m < 4; ++m) {
#pragma unroll
      for (int j = 0; j < 4; ++j) {
        int row = m0 + wm + (m << 4) + (kg << 2) + j;
        if (row < M) {
          float v = acc[m][n][j] + bv;
          if (relu) v = fmaxf(v, 0.f);
          unsigned short h = f2bf(v);
          C[(size_t)row * N + col] = *(__bf16*)&h;
        }
      }
    }
  }
}

extern "C" void kernel_launch(void* const* d_in, const int* in_sizes, int n_in,
                              void* d_out, int out_size, void* d_ws, size_t ws_size,
                              hipStream_t stream) {
  const float* features = (const float*)d_in[0];
  const float* W1 = (const float*)d_in[1];
  const float* b1 = (const float*)d_in[2];
  const float* W2 = (const float*)d_in[3];
  const float* b2 = (const float*)d_in[4];
  const int* ei = (const int*)d_in[5];
  float* out = (float*)d_out;

  char* ws = (char*)d_ws;
  size_t off = 0;
  auto alloc = [&](size_t bytes) -> void* {
    void* p = ws + off;
    off += (bytes + 255) & ~(size_t)255;
    return p;
  };
  int* degi_out = (int*)alloc((size_t)NNODES * 4);
  int* degi_in  = (int*)alloc((size_t)NNODES * 4);
  float* onorm  = (float*)alloc((size_t)NNODES * 4);
  float* inorm  = (float*)alloc((size_t)NNODES * 4);
  int* row_ptr  = (int*)alloc((size_t)(NNODES + 1) * 4);
  int* cursor   = (int*)alloc((size_t)NNODES * 4);
  int* csr_src  = (int*)alloc((size_t)NEDGES * 4);
  unsigned* featb = (unsigned*)alloc((size_t)NNODES * FIN * 2);
  unsigned* aggF  = (unsigned*)alloc((size_t)NNODES * FIN * 2);
  __bf16* h1 = (__bf16*)alloc((size_t)NNODES * FHID * 2);
  __bf16* h2 = (__bf16*)alloc((size_t)NNODES * FOUT * 2);
  __bf16* W1t = (__bf16*)alloc((size_t)FIN * FHID * 2);
  __bf16* W2t = (__bf16*)alloc((size_t)FHID * FOUT * 2);
  (void)ws_size; (void)n_in; (void)in_sizes; (void)out_size;

  // zero degree counters (degi_out and degi_in are contiguous padded regions)
  hipMemsetAsync(degi_out, 0, 2 * (((size_t)NNODES * 4 + 255) & ~(size_t)255), stream);

  // converts
  cvt_feat_kernel<<<(NNODES * FIN / 4 + 255) / 256, 256, 0, stream>>>(features, featb, NNODES * FIN / 4);
  wt_kernel<<<(FIN * FHID + 255) / 256, 256, 0, stream>>>(W1, W1t, FIN, FHID);
  wt_kernel<<<(FHID * FOUT + 255) / 256, 256, 0, stream>>>(W2, W2t, FHID, FOUT);

  // graph preprocessing
  degree_kernel<<<(NEDGES + 255) / 256, 256, 0, stream>>>(ei, degi_out, degi_in);
  norm_kernel<<<(NNODES + 255) / 256, 256, 0, stream>>>(degi_out, degi_in, onorm, inorm);
  scan_kernel<<<1, 1024, 0, stream>>>(degi_in, row_ptr, cursor, NNODES);
  fill_kernel<<<(NEDGES + 255) / 256, 256, 0, stream>>>(ei, cursor, csr_src);

  // conv1: aggregate then transform (+bias, relu)
  agg1_kernel<<<(NNODES + 3) / 4, 256, 0, stream>>>(row_ptr, csr_src, onorm, inorm, featb, aggF);
  gemm_bf16<<<dim3((NNODES + 127) / 128, FHID / 128), 256, 0, stream>>>(
      (const __bf16*)aggF, W1t, b1, h1, NNODES, FHID, FIN, 1);

  // conv2: transform then aggregate (+b2 after aggregate)
  gemm_bf16<<<dim3((NNODES + 127) / 128, FOUT / 128), 256, 0, stream>>>(
      h1, W2t, nullptr, h2, NNODES, FOUT, FHID, 0);
  agg2_kernel<<<(NNODES + 3) / 4, 256, 0, stream>>>(row_ptr, csr_src, onorm, inorm,
                                                    (const unsigned*)h2, b2, out);
}

// Round 2
// 403.432 us; speedup vs baseline: 1.2796x; 1.2796x over previous
//
#include <hip/hip_runtime.h>
#include <hip/hip_bf16.h>

typedef float f32x4 __attribute__((ext_vector_type(4)));
typedef __bf16 bf16x8 __attribute__((ext_vector_type(8)));

#define NNODES 50000
#define NEDGES 800000
#define FIN 128
#define FHID 384
#define FOUT 256

// scan geometry: 49 blocks x 256 threads x 4 elements
#define SCAN_NB ((NNODES + 1023) / 1024)

__device__ __forceinline__ float bf_lo(unsigned u) { return __uint_as_float(u << 16); }
__device__ __forceinline__ float bf_hi(unsigned u) { return __uint_as_float(u & 0xffff0000u); }
__device__ __forceinline__ unsigned short f2bf(float f) {
  unsigned u = __float_as_uint(f);
  u += 0x7fffu + ((u >> 16) & 1u);
  return (unsigned short)(u >> 16);
}

// ---------- feature f32 -> bf16 (packed pairs in uint) ----------
__global__ void cvt_feat_kernel(const float* __restrict__ f, unsigned* __restrict__ o, int n4) {
  int i = blockIdx.x * blockDim.x + threadIdx.x;
  if (i >= n4) return;
  float4 v = *(const float4*)(f + (size_t)i * 4);
  unsigned lo = (unsigned)f2bf(v.x) | ((unsigned)f2bf(v.y) << 16);
  unsigned hi = (unsigned)f2bf(v.z) | ((unsigned)f2bf(v.w) << 16);
  *(uint2*)(o + (size_t)i * 2) = make_uint2(lo, hi);
}

// ---------- W [K][Nw] f32 -> Wt [Nw][K] bf16 ----------
__global__ void wt_kernel(const float* __restrict__ W, __bf16* __restrict__ Wt, int K, int Nw) {
  int i = blockIdx.x * blockDim.x + threadIdx.x;
  if (i >= K * Nw) return;
  int k = i / Nw, n = i % Nw;
  unsigned short b = f2bf(W[i]);
  Wt[(size_t)n * K + k] = *(__bf16*)&b;
}

// ---------- degrees ----------
__global__ void degree_kernel(const int* __restrict__ ei, int* __restrict__ dout, int* __restrict__ din) {
  int e = blockIdx.x * blockDim.x + threadIdx.x;
  if (e >= NEDGES) return;
  atomicAdd(&dout[ei[e]], 1);
  atomicAdd(&din[ei[NEDGES + e]], 1);
}

// ---------- norms = clip(deg,1)^-0.5 ----------
__global__ void norm_kernel(const int* __restrict__ dout, const int* __restrict__ din,
                            float* __restrict__ onorm, float* __restrict__ inorm) {
  int i = blockIdx.x * blockDim.x + threadIdx.x;
  if (i >= NNODES) return;
  int a = dout[i]; if (a < 1) a = 1;
  int b = din[i]; if (b < 1) b = 1;
  onorm[i] = rsqrtf((float)a);
  inorm[i] = rsqrtf((float)b);
}

// ---------- multi-block exclusive scan, stage 1: per-block sums ----------
__global__ __launch_bounds__(256) void scan_part1(const int* __restrict__ deg,
                                                  int* __restrict__ blocksums) {
  int b = blockIdx.x, t = threadIdx.x;
  int base = b * 1024 + t * 4;
  int s = 0;
  if (base + 4 <= NNODES) {
    int4 v = *(const int4*)(deg + base);
    s = v.x + v.y + v.z + v.w;
  } else {
    for (int j = 0; j < 4; ++j)
      if (base + j < NNODES) s += deg[base + j];
  }
  // wave inclusive scan not needed; just reduce
  for (int d = 32; d >= 1; d >>= 1) s += __shfl_down(s, d, 64);
  __shared__ int ws[4];
  int lane = t & 63, w = t >> 6;
  if (lane == 0) ws[w] = s;
  __syncthreads();
  if (t == 0) blocksums[b] = ws[0] + ws[1] + ws[2] + ws[3];
}

// ---------- stage 2: one wave scans the block sums (SCAN_NB <= 64) ----------
__global__ void scan_mid(const int* __restrict__ bs, int* __restrict__ boff) {
  int t = threadIdx.x;  // 64 threads
  int v = (t < SCAN_NB) ? bs[t] : 0;
  int x = v;
  for (int d = 1; d < 64; d <<= 1) {
    int y = __shfl_up(x, d, 64);
    if (t >= d) x += y;
  }
  if (t < SCAN_NB) boff[t] = x - v;  // exclusive
}

// ---------- stage 3: intra-block exclusive scan + write row_ptr/cursor ----------
__global__ __launch_bounds__(256) void scan_part2(const int* __restrict__ deg,
                                                  const int* __restrict__ boff,
                                                  int* __restrict__ row_ptr,
                                                  int* __restrict__ cursor) {
  int b = blockIdx.x, t = threadIdx.x;
  int base = b * 1024 + t * 4;
  int v0 = 0, v1 = 0, v2 = 0, v3 = 0;
  if (base + 4 <= NNODES) {
    int4 v = *(const int4*)(deg + base);
    v0 = v.x; v1 = v.y; v2 = v.z; v3 = v.w;
  } else {
    if (base + 0 < NNODES) v0 = deg[base + 0];
    if (base + 1 < NNODES) v1 = deg[base + 1];
    if (base + 2 < NNODES) v2 = deg[base + 2];
    if (base + 3 < NNODES) v3 = deg[base + 3];
  }
  int s = v0 + v1 + v2 + v3;
  // inclusive wave scan of s
  int x = s;
  int lane = t & 63, w = t >> 6;
  for (int d = 1; d < 64; d <<= 1) {
    int y = __shfl_up(x, d, 64);
    if (lane >= d) x += y;
  }
  __shared__ int ws[4];
  if (lane == 63) ws[w] = x;
  __syncthreads();
  int woff = 0;
  for (int i = 0; i < w; ++i) woff += ws[i];
  int off = boff[b] + woff + (x - s);  // exclusive prefix for this thread
  if (base + 0 < NNODES) { row_ptr[base + 0] = off; cursor[base + 0] = off; off += v0; }
  if (base + 1 < NNODES) { row_ptr[base + 1] = off; cursor[base + 1] = off; off += v1; }
  if (base + 2 < NNODES) { row_ptr[base + 2] = off; cursor[base + 2] = off; off += v2; }
  if (base + 3 < NNODES) { row_ptr[base + 3] = off; cursor[base + 3] = off; off += v3; }
  if (base < NNODES && base + 4 >= NNODES) row_ptr[NNODES] = off;  // thread owning last elem
}

// ---------- CSR fill (bucket by dst) ----------
__global__ void fill_kernel(const int* __restrict__ ei, int* __restrict__ cursor, int* __restrict__ csr) {
  int e = blockIdx.x * blockDim.x + threadIdx.x;
  if (e >= NEDGES) return;
  int d = ei[NEDGES + e];
  int pos = atomicAdd(&cursor[d], 1);
  csr[pos] = ei[e];
}

// ---------- aggregate 1: aggF[n] = in_norm[n] * sum_e out_norm[src]*feat[src], d=128, bf16 out ----------
__global__ __launch_bounds__(256) void agg1_kernel(
    const int* __restrict__ row_ptr, const int* __restrict__ csr_src,
    const float* __restrict__ onorm, const float* __restrict__ inorm,
    const unsigned* __restrict__ featb, unsigned* __restrict__ aggF) {
  int node = (blockIdx.x << 2) + (threadIdx.x >> 6);
  if (node >= NNODES) return;
  int lane = threadIdx.x & 63;
  int beg = row_ptr[node], end = row_ptr[node + 1];
  float a0 = 0.f, a1 = 0.f;
  int e = beg;
  for (; e + 2 <= end; e += 2) {
    int s0 = csr_src[e], s1 = csr_src[e + 1];
    float w0 = onorm[s0], w1 = onorm[s1];
    unsigned p0 = featb[(size_t)s0 * 64 + lane];
    unsigned p1 = featb[(size_t)s1 * 64 + lane];
    a0 = fmaf(w0, bf_lo(p0), a0); a1 = fmaf(w0, bf_hi(p0), a1);
    a0 = fmaf(w1, bf_lo(p1), a0); a1 = fmaf(w1, bf_hi(p1), a1);
  }
  if (e < end) {
    int s0 = csr_src[e];
    float w0 = onorm[s0];
    unsigned p0 = featb[(size_t)s0 * 64 + lane];
    a0 = fmaf(w0, bf_lo(p0), a0); a1 = fmaf(w0, bf_hi(p0), a1);
  }
  float inn = inorm[node];
  a0 *= inn; a1 *= inn;
  aggF[(size_t)node * 64 + lane] = (unsigned)f2bf(a0) | ((unsigned)f2bf(a1) << 16);
}

// ---------- aggregate 2: out[n] = in_norm[n]*sum_e out_norm[src]*h2[src] + b2, d=256, f32 out ----------
__global__ __launch_bounds__(256) void agg2_kernel(
    const int* __restrict__ row_ptr, const int* __restrict__ csr_src,
    const float* __restrict__ onorm, const float* __restrict__ inorm,
    const unsigned* __restrict__ h2u, const float* __restrict__ b2,
    float* __restrict__ out) {
  int node = (blockIdx.x << 2) + (threadIdx.x >> 6);
  if (node >= NNODES) return;
  int lane = threadIdx.x & 63;
  int beg = row_ptr[node], end = row_ptr[node + 1];
  float a0 = 0.f, a1 = 0.f, a2 = 0.f, a3 = 0.f;
  int e = beg;
  for (; e + 2 <= end; e += 2) {
    int s0 = csr_src[e], s1 = csr_src[e + 1];
    float w0 = onorm[s0], w1 = onorm[s1];
    uint2 q0 = *(const uint2*)(h2u + (size_t)s0 * 128 + (lane << 1));
    uint2 q1 = *(const uint2*)(h2u + (size_t)s1 * 128 + (lane << 1));
    a0 = fmaf(w0, bf_lo(q0.x), a0); a1 = fmaf(w0, bf_hi(q0.x), a1);
    a2 = fmaf(w0, bf_lo(q0.y), a2); a3 = fmaf(w0, bf_hi(q0.y), a3);
    a0 = fmaf(w1, bf_lo(q1.x), a0); a1 = fmaf(w1, bf_hi(q1.x), a1);
    a2 = fmaf(w1, bf_lo(q1.y), a2); a3 = fmaf(w1, bf_hi(q1.y), a3);
  }
  if (e < end) {
    int s0 = csr_src[e];
    float w0 = onorm[s0];
    uint2 q0 = *(const uint2*)(h2u + (size_t)s0 * 128 + (lane << 1));
    a0 = fmaf(w0, bf_lo(q0.x), a0); a1 = fmaf(w0, bf_hi(q0.x), a1);
    a2 = fmaf(w0, bf_lo(q0.y), a2); a3 = fmaf(w0, bf_hi(q0.y), a3);
  }
  float inn = inorm[node];
  float4 bv = *(const float4*)(b2 + (lane << 2));
  float4 r;
  r.x = fmaf(a0, inn, bv.x);
  r.y = fmaf(a1, inn, bv.y);
  r.z = fmaf(a2, inn, bv.z);
  r.w = fmaf(a3, inn, bv.w);
  *(float4*)(out + (size_t)node * FOUT + (lane << 2)) = r;
}

// ---------- GEMM: C[M][N](bf16) = A[M][K](bf16) @ Bt[N][K](bf16)^T, opt bias+relu ----------
__device__ __forceinline__ f32x4 mfma16(bf16x8 a, bf16x8 b, f32x4 c) {
  return __builtin_amdgcn_mfma_f32_16x16x32_bf16(a, b, c, 0, 0, 0);
}

__global__ __launch_bounds__(256) void gemm_bf16(
    const __bf16* __restrict__ A, const __bf16* __restrict__ Bt,
    const float* __restrict__ bias, __bf16* __restrict__ C,
    int M, int N, int K, int relu) {
  __shared__ __attribute__((aligned(16))) __bf16 As[128 * 64];
  __shared__ __attribute__((aligned(16))) __bf16 Bs[128 * 64];
  const int tid = threadIdx.x;
  const int lane = tid & 63;
  const int wave = tid >> 6;
  const int wm = (wave >> 1) << 6;
  const int wn = (wave & 1) << 6;
  const int r16 = lane & 15;
  const int kg = lane >> 4;
  const int m0 = blockIdx.x * 128;
  const int n0 = blockIdx.y * 128;
  f32x4 acc[4][4];
#pragma unroll
  for (int m = 0; m < 4; ++m)
#pragma unroll
    for (int n = 0; n < 4; ++n) acc[m][n] = f32x4{0.f, 0.f, 0.f, 0.f};

  for (int k0 = 0; k0 < K; k0 += 64) {
    __syncthreads();
#pragma unroll
    for (int i = 0; i < 4; ++i) {
      int c = tid + (i << 8);      // chunk 0..1023
      int row = c >> 3;            // 0..127
      int col = c & 7;             // 16B chunk in row
      int sw = ((col ^ (row & 7)) << 3);
      int ga = m0 + row;
      uint4 av = make_uint4(0u, 0u, 0u, 0u);
      if (ga < M) av = *(const uint4*)(A + (size_t)ga * K + k0 + (col << 3));
      *(uint4*)(As + row * 64 + sw) = av;
      uint4 bv = *(const uint4*)(Bt + (size_t)(n0 + row) * K + k0 + (col << 3));
      *(uint4*)(Bs + row * 64 + sw) = bv;
    }
    __syncthreads();
#pragma unroll
    for (int kk = 0; kk < 2; ++kk) {
      int kc = (kk << 2) + kg;   // logical 16B chunk 0..7
      bf16x8 a[4], b[4];
#pragma unroll
      for (int m = 0; m < 4; ++m) {
        int r = wm + (m << 4) + r16;
        a[m] = *(const bf16x8*)(As + r * 64 + ((kc ^ (r & 7)) << 3));
      }
#pragma unroll
      for (int n = 0; n < 4; ++n) {
        int r = wn + (n << 4) + r16;
        b[n] = *(const bf16x8*)(Bs + r * 64 + ((kc ^ (r & 7)) << 3));
      }
#pragma unroll
      for (int m = 0; m < 4; ++m)
#pragma unroll
        for (int n = 0; n < 4; ++n)
          acc[m][n] = mfma16(a[m], b[n], acc[m][n]);
    }
  }
  // epilogue: C row = m0+wm+m*16+kg*4+j, col = n0+wn+n*16+r16
#pragma unroll
  for (int n = 0; n < 4; ++n) {
    int col = n0 + wn + (n << 4) + r16;
    float bv = bias ? bias[col] : 0.f;
#pragma unroll
    for (int m = 0; m < 4; ++m) {
#pragma unroll
      for (int j = 0; j < 4; ++j) {
        int row = m0 + wm + (m << 4) + (kg << 2) + j;
        if (row < M) {
          float v = acc[m][n][j] + bv;
          if (relu) v = fmaxf(v, 0.f);
          unsigned short h = f2bf(v);
          C[(size_t)row * N + col] = *(__bf16*)&h;
        }
      }
    }
  }
}

extern "C" void kernel_launch(void* const* d_in, const int* in_sizes, int n_in,
                              void* d_out, int out_size, void* d_ws, size_t ws_size,
                              hipStream_t stream) {
  const float* features = (const float*)d_in[0];
  const float* W1 = (const float*)d_in[1];
  const float* b1 = (const float*)d_in[2];
  const float* W2 = (const float*)d_in[3];
  const float* b2 = (const float*)d_in[4];
  const int* ei = (const int*)d_in[5];
  float* out = (float*)d_out;

  char* ws = (char*)d_ws;
  size_t off = 0;
  auto alloc = [&](size_t bytes) -> void* {
    void* p = ws + off;
    off += (bytes + 255) & ~(size_t)255;
    return p;
  };
  int* degi_out = (int*)alloc((size_t)NNODES * 4);
  int* degi_in  = (int*)alloc((size_t)NNODES * 4);
  float* onorm  = (float*)alloc((size_t)NNODES * 4);
  float* inorm  = (float*)alloc((size_t)NNODES * 4);
  int* row_ptr  = (int*)alloc((size_t)(NNODES + 1) * 4);
  int* cursor   = (int*)alloc((size_t)NNODES * 4);
  int* csr_src  = (int*)alloc((size_t)NEDGES * 4);
  int* blocksums = (int*)alloc((size_t)SCAN_NB * 4);
  int* blockoffs = (int*)alloc((size_t)SCAN_NB * 4);
  unsigned* featb = (unsigned*)alloc((size_t)NNODES * FIN * 2);
  unsigned* aggF  = (unsigned*)alloc((size_t)NNODES * FIN * 2);
  __bf16* h1 = (__bf16*)alloc((size_t)NNODES * FHID * 2);
  __bf16* h2 = (__bf16*)alloc((size_t)NNODES * FOUT * 2);
  __bf16* W1t = (__bf16*)alloc((size_t)FIN * FHID * 2);
  __bf16* W2t = (__bf16*)alloc((size_t)FHID * FOUT * 2);
  (void)ws_size; (void)n_in; (void)in_sizes; (void)out_size;

  // zero degree counters (degi_out and degi_in are contiguous padded regions)
  hipMemsetAsync(degi_out, 0, 2 * (((size_t)NNODES * 4 + 255) & ~(size_t)255), stream);

  // converts
  cvt_feat_kernel<<<(NNODES * FIN / 4 + 255) / 256, 256, 0, stream>>>(features, featb, NNODES * FIN / 4);
  wt_kernel<<<(FIN * FHID + 255) / 256, 256, 0, stream>>>(W1, W1t, FIN, FHID);
  wt_kernel<<<(FHID * FOUT + 255) / 256, 256, 0, stream>>>(W2, W2t, FHID, FOUT);

  // graph preprocessing
  degree_kernel<<<(NEDGES + 255) / 256, 256, 0, stream>>>(ei, degi_out, degi_in);
  norm_kernel<<<(NNODES + 255) / 256, 256, 0, stream>>>(degi_out, degi_in, onorm, inorm);
  scan_part1<<<SCAN_NB, 256, 0, stream>>>(degi_in, blocksums);
  scan_mid<<<1, 64, 0, stream>>>(blocksums, blockoffs);
  scan_part2<<<SCAN_NB, 256, 0, stream>>>(degi_in, blockoffs, row_ptr, cursor);
  fill_kernel<<<(NEDGES + 255) / 256, 256, 0, stream>>>(ei, cursor, csr_src);

  // conv1: aggregate then transform (+bias, relu)
  agg1_kernel<<<(NNODES + 3) / 4, 256, 0, stream>>>(row_ptr, csr_src, onorm, inorm, featb, aggF);
  gemm_bf16<<<dim3((NNODES + 127) / 128, FHID / 128), 256, 0, stream>>>(
      (const __bf16*)aggF, W1t, b1, h1, NNODES, FHID, FIN, 1);

  // conv2: transform then aggregate (+b2 after aggregate)
  gemm_bf16<<<dim3((NNODES + 127) / 128, FOUT / 128), 256, 0, stream>>>(
      h1, W2t, nullptr, h2, NNODES, FOUT, FHID, 0);
  agg2_kernel<<<(NNODES + 3) / 4, 256, 0, stream>>>(row_ptr, csr_src, onorm, inorm,
                                                    (const unsigned*)h2, b2, out);
}